// Round 5
// baseline (39008.585 us; speedup 1.0000x reference)
//
#include <hip/hip_runtime.h>
#include <math.h>

// Persistent cooperative LSTM: 256 WGs x 512 threads, 1 WG/CU.
// WG w owns hidden units [8w, 8w+8). wave u = unit, 16-lane group g = gate.
// Folded weights W' = W_hh + (w1+w2) (x) W_lin in regs (128/thread).
// __launch_bounds__(512,1): 2 waves/SIMD -> 256-VGPR budget so wreg[] does
// NOT spill (launch_bounds 2nd arg is min BLOCKS/CU in HIP; (512,2) capped
// VGPRs at 128 and spilled the whole weight array to scratch in R1-R4).
//
// Per-step protocol (minimal fabric load):
//   1. matvec from h_lds[rb] -> gates -> h_new
//   2. lane0/wave: relaxed agent store h_new (plain f32) -> h_glob[t&1][unit]
//   3. __syncthreads (#1): every wave's store acked (per-wave vmcnt drain)
//   4. tid0: ONE release fetch_add to cnt[t&1][wg>>3] (32 cells, 16B pad)
//   5. wave0 polls the 32 cells (512B footprint/round, s_sleep-throttled)
//      until all >= 8*((t>>1)+1)
//   6. __syncthreads (#2), then ALL threads bulk-pull h_t once:
//      2 relaxed agent u64 loads/thread (coalesced 8 KB/WG), write h_lds[t&1]
//   7. __syncthreads (#3)
// No tags needed: release-add happens-after h stores; per-parity counters
// + program order (add_{t+1} is after pull_t drained at barrier #3) make
// false-positives and double-buffer overwrite impossible.
//
// y_t: owner WG (t%256) dots pulled registers with W_lin, ds-atomicAdd into
// y_acc, wave7 writes out[t] during step t+1 (off critical path).

#define HDIM 2048
#define TSTEPS 4096
#define NWG 256
#define NTH 512  // 8 waves

typedef unsigned long long u64;
typedef unsigned int u32;

__device__ __forceinline__ float sigmoidf_(float x) {
    return 1.0f / (1.0f + expf(-x));
}

__global__ __launch_bounds__(NTH, 1)
void weld_lstm_persistent(const float* __restrict__ src,
                          const float* __restrict__ W_ih,
                          const float* __restrict__ W_hh,
                          const float* __restrict__ b_ih,
                          const float* __restrict__ b_hh,
                          const float* __restrict__ W_lin,
                          const float* __restrict__ b_lin,
                          float* __restrict__ out,
                          u32* __restrict__ cnt,      // 2 x 32 cells x 16B
                          float* __restrict__ h_glob) // 2 x 2048 f32
{
    __shared__ float h_lds[2][HDIM];
    __shared__ float s_lds[TSTEPS];
    __shared__ float wlin_lds[HDIM];
    __shared__ float y_acc;

    const int wg   = blockIdx.x;
    const int tid  = threadIdx.x;
    const int wave = tid >> 6;
    const int lane = tid & 63;
    const int g    = lane >> 4;        // gate 0..3 (i,f,g,o)
    const int sub  = lane & 15;
    const int unit = wg * 8 + wave;
    const int row  = g * HDIM + unit;
    const int cell = wg >> 3;          // 8 WGs per counter cell

    for (int i = tid; i < TSTEPS; i += NTH) s_lds[i] = src[3 * i];
    for (int i = tid; i < HDIM;   i += NTH) wlin_lds[i] = W_lin[i];
    if (tid == 0) y_acc = 0.0f;

    const float s01  = src[1];
    const float s02  = src[2];
    const float blin = b_lin[0];

    const float w0    = W_ih[row * 3 + 0];
    const float w1    = W_ih[row * 3 + 1];
    const float w2    = W_ih[row * 3 + 2];
    const float w12   = w1 + w2;
    const float braw  = b_ih[row] + b_hh[row];
    const float bfold = braw + w12 * blin;

    // Folded weights W'[row,c] = W_hh[row,c] + w12*W_lin[c]; this lane's
    // columns: c = k*64 + sub*4 + {0..3}, k = 0..31. Fully unrolled,
    // compile-time indices -> stays in VGPRs under the 256-reg budget.
    float wreg[128];
    {
        const float* wrow = W_hh + (size_t)row * HDIM;
        #pragma unroll
        for (int k = 0; k < 32; ++k) {
            const int c = k * 64 + sub * 4;
            float4 wv = *reinterpret_cast<const float4*>(wrow + c);
            float4 lv = *reinterpret_cast<const float4*>(W_lin + c);
            wreg[k * 4 + 0] = wv.x + w12 * lv.x;
            wreg[k * 4 + 1] = wv.y + w12 * lv.y;
            wreg[k * 4 + 2] = wv.z + w12 * lv.z;
            wreg[k * 4 + 3] = wv.w + w12 * lv.w;
        }
    }

    __syncthreads();

    float c_state = 0.0f;

    // bulk-pull mapping: thread pulls floats [tid*4, tid*4+4)
    const float4 wl = *reinterpret_cast<const float4*>(&wlin_lds[tid * 4]);

    for (int t = 0; t < TSTEPS; ++t) {
        const int wb = t & 1;
        const int rb = wb ^ 1;

        float xterm;
        if (t == 0) {
            xterm = braw + w0 * s_lds[0] + w1 * s01 + w2 * s02;
        } else {
            xterm = bfold + w0 * s_lds[t];
        }

        float sum = 0.0f;
        if (t > 0) {
            float a0 = 0.0f, a1 = 0.0f, a2 = 0.0f, a3 = 0.0f;
            #pragma unroll
            for (int k = 0; k < 32; ++k) {
                const int col = k * 64 + sub * 4;
                float4 h4 = *reinterpret_cast<const float4*>(&h_lds[rb][col]);
                a0 += wreg[k * 4 + 0] * h4.x;
                a1 += wreg[k * 4 + 1] * h4.y;
                a2 += wreg[k * 4 + 2] * h4.z;
                a3 += wreg[k * 4 + 3] * h4.w;
            }
            sum = (a0 + a1) + (a2 + a3);
            sum += __shfl_xor(sum, 1);
            sum += __shfl_xor(sum, 2);
            sum += __shfl_xor(sum, 4);
            sum += __shfl_xor(sum, 8);
        }

        // finalize y_{t-1} (partials all landed before iter t-1's barrier #3)
        if (t > 0 && wg == ((t - 1) & (NWG - 1)) && wave == 7 && lane == 0) {
            out[t - 1] = y_acc + blin;
            y_acc = 0.0f;  // next partials for this WG: step t+255
        }

        const float gate = sum + xterm;
        const float gi = __shfl(gate, 0);
        const float gf = __shfl(gate, 16);
        const float gg = __shfl(gate, 32);
        const float go = __shfl(gate, 48);
        c_state = sigmoidf_(gf) * c_state + sigmoidf_(gi) * tanhf(gg);
        const float h_new = sigmoidf_(go) * tanhf(c_state);

        // publish h_t[unit] (plain f32, coherence-point store)
        float* hb = h_glob + (size_t)wb * HDIM;
        if (lane == 0) {
            __hip_atomic_store(&hb[unit], h_new,
                               __ATOMIC_RELAXED, __HIP_MEMORY_SCOPE_AGENT);
        }

        __syncthreads();  // #1: all 8 waves' stores acked (per-wave vmcnt(0))

        if (tid == 0) {
            // one release-add per WG; orders this WG's 8 stores before the
            // counter increment at the coherence point
            __hip_atomic_fetch_add(&cnt[(size_t)(wb * 32 + cell) * 4], 1u,
                                   __ATOMIC_RELEASE, __HIP_MEMORY_SCOPE_AGENT);
        }

        // wave0 polls the 32 cells; everyone else waits at barrier #2
        if (wave == 0) {
            const u32 need = (u32)(((t >> 1) + 1) << 3);  // 8 per cell
            const size_t ci = (size_t)(wb * 32 + (lane & 31)) * 4;
            for (;;) {
                const u32 v = __hip_atomic_load(&cnt[ci], __ATOMIC_RELAXED,
                                                __HIP_MEMORY_SCOPE_AGENT);
                if (__all(v >= need)) break;
                __builtin_amdgcn_s_sleep(1);
            }
        }
        __syncthreads();  // #2: counter condition holds for the whole WG

        // single-shot bulk pull of h_t: 2 coalesced u64 loads per thread
        const u64* hb64 = (const u64*)hb;
        const u64 p0 = __hip_atomic_load(&hb64[tid * 2 + 0], __ATOMIC_RELAXED,
                                         __HIP_MEMORY_SCOPE_AGENT);
        const u64 p1 = __hip_atomic_load(&hb64[tid * 2 + 1], __ATOMIC_RELAXED,
                                         __HIP_MEMORY_SCOPE_AGENT);
        const float f0 = __uint_as_float((u32)p0);
        const float f1 = __uint_as_float((u32)(p0 >> 32));
        const float f2 = __uint_as_float((u32)p1);
        const float f3 = __uint_as_float((u32)(p1 >> 32));
        float4 hv; hv.x = f0; hv.y = f1; hv.z = f2; hv.w = f3;
        *reinterpret_cast<float4*>(&h_lds[wb][tid * 4]) = hv;

        // y_t partial from registers (owner WG only)
        if (wg == (t & (NWG - 1))) {
            float yp = f0 * wl.x + f1 * wl.y + f2 * wl.z + f3 * wl.w;
            yp += __shfl_xor(yp, 1);
            yp += __shfl_xor(yp, 2);
            yp += __shfl_xor(yp, 4);
            yp += __shfl_xor(yp, 8);
            yp += __shfl_xor(yp, 16);
            yp += __shfl_xor(yp, 32);
            if (lane == 0) atomicAdd(&y_acc, yp);
        }

        __syncthreads();  // #3: h_lds[wb] complete; drains pulls (reuse-safe)
    }

    // final y_{T-1}: owner wg = 255
    if (wg == ((TSTEPS - 1) & (NWG - 1)) && wave == 7 && lane == 0) {
        out[TSTEPS - 1] = y_acc + blin;
    }
}

extern "C" void kernel_launch(void* const* d_in, const int* in_sizes, int n_in,
                              void* d_out, int out_size, void* d_ws, size_t ws_size,
                              hipStream_t stream) {
    const float* src   = (const float*)d_in[0];
    const float* W_ih  = (const float*)d_in[1];
    const float* W_hh  = (const float*)d_in[2];
    const float* b_ih  = (const float*)d_in[3];
    const float* b_hh  = (const float*)d_in[4];
    const float* W_lin = (const float*)d_in[5];
    const float* b_lin = (const float*)d_in[6];
    float* out = (float*)d_out;

    // ws: [0, 1 KiB)      cnt: 2 parity x 32 cells x 16 B (u32 + pad)
    //     [4 KiB, 20 KiB) h_glob: 2 parity x 2048 f32
    // cnt must be zeroed every launch (graph replay) — h_glob needs no init
    // (reads are gated by cnt, which is reset).
    u32*   cnt    = (u32*)d_ws;
    float* h_glob = (float*)((char*)d_ws + 4096);
    hipMemsetAsync(d_ws, 0, 1024, stream);

    void* args[] = { &src, &W_ih, &W_hh, &b_ih, &b_hh, &W_lin, &b_lin,
                     &out, &cnt, &h_glob };
    hipLaunchCooperativeKernel((const void*)weld_lstm_persistent,
                               dim3(NWG), dim3(NTH), args, 0, stream);
}

// Round 6
// 24898.843 us; speedup vs baseline: 1.5667x; 1.5667x over previous
//
#include <hip/hip_runtime.h>
#include <math.h>

// Persistent cooperative LSTM: 256 WGs x 512 threads, 1 WG/CU.
// WG w owns hidden units [8w, 8w+8). wave u = unit, 16-lane group g = gate.
// Folded weights W' = W_hh + (w1+w2) (x) W_lin : 128 per thread, PINNED IN
// AGPRS via v_accvgpr_write/read inline asm ("a" constraints). R1-R5 showed
// VGPR_Count=112 every round: the compiler never kept wreg[128] in registers
// (spill/remat -> ~256KB/CU/step of scratch-L2 reloads on the critical
// path). AGPR pinning makes spilling impossible; volatile per-use reads keep
// VGPR pressure ~60 so occupancy (2 waves/SIMD) is unaffected.
//
// Protocol (= R4, best measured): producer lane0 stores fused
// ((t+1)<<32 | f32bits(h)) to h_buf[t&1][unit]; all threads poll 4 coalesced
// units (wave*256+lane+64j) until tag==t+1 (s_sleep-throttled), write them
// to h_lds[t&1]; ONE __syncthreads; next matvec reads h_lds. Exact-tag match
// + per-parity buffers kill ABA; memset per launch kills replay staleness.
//
// y_t: owner WG (t%256) dots pulled registers with W_lin into LDS y_acc;
// its wave7 writes out[t] during step t+1 (off the critical path).

#define HDIM 2048
#define TSTEPS 4096
#define NWG 256
#define NTH 512  // 8 waves

typedef unsigned long long u64;
typedef unsigned int u32;

__device__ __forceinline__ float sigmoidf_(float x) {
    return 1.0f / (1.0f + expf(-x));
}

#define FOR_K(X) X(0) X(1) X(2) X(3) X(4) X(5) X(6) X(7) \
                 X(8) X(9) X(10) X(11) X(12) X(13) X(14) X(15) \
                 X(16) X(17) X(18) X(19) X(20) X(21) X(22) X(23) \
                 X(24) X(25) X(26) X(27) X(28) X(29) X(30) X(31)

// declare 4 AGPR-resident floats per k (one per float4 component)
#define DECLW(k) float agx##k, agy##k, agz##k, agw##k;

// init: load W_hh/W_lin slices, fold, write into AGPRs
#define INITW(k) { \
    const int c_ = (k) * 64 + sub * 4; \
    float4 wv = *reinterpret_cast<const float4*>(wrow + c_); \
    float4 lv = *reinterpret_cast<const float4*>(W_lin + c_); \
    asm volatile("v_accvgpr_write_b32 %0, %1" : "=a"(agx##k) : "v"(wv.x + w12 * lv.x)); \
    asm volatile("v_accvgpr_write_b32 %0, %1" : "=a"(agy##k) : "v"(wv.y + w12 * lv.y)); \
    asm volatile("v_accvgpr_write_b32 %0, %1" : "=a"(agz##k) : "v"(wv.z + w12 * lv.z)); \
    asm volatile("v_accvgpr_write_b32 %0, %1" : "=a"(agw##k) : "v"(wv.w + w12 * lv.w)); \
}

// matvec term: read 4 weights back (volatile: re-read each step, keeps VGPR
// pressure low) and FMA against the h_lds float4
#define MACW(k) { \
    const int col_ = (k) * 64 + sub * 4; \
    float4 h4 = *reinterpret_cast<const float4*>(&h_lds[rb][col_]); \
    float wx_, wy_, wz_, ww_; \
    asm volatile("v_accvgpr_read_b32 %0, %1" : "=v"(wx_) : "a"(agx##k)); \
    asm volatile("v_accvgpr_read_b32 %0, %1" : "=v"(wy_) : "a"(agy##k)); \
    asm volatile("v_accvgpr_read_b32 %0, %1" : "=v"(wz_) : "a"(agz##k)); \
    asm volatile("v_accvgpr_read_b32 %0, %1" : "=v"(ww_) : "a"(agw##k)); \
    a0 += wx_ * h4.x; a1 += wy_ * h4.y; a2 += wz_ * h4.z; a3 += ww_ * h4.w; \
}

__global__ __launch_bounds__(NTH, 2)
void weld_lstm_persistent(const float* __restrict__ src,
                          const float* __restrict__ W_ih,
                          const float* __restrict__ W_hh,
                          const float* __restrict__ b_ih,
                          const float* __restrict__ b_hh,
                          const float* __restrict__ W_lin,
                          const float* __restrict__ b_lin,
                          float* __restrict__ out,
                          u64* __restrict__ h_buf)
{
    __shared__ float h_lds[2][HDIM];
    __shared__ float s_lds[TSTEPS];
    __shared__ float wlin_lds[HDIM];
    __shared__ float y_acc;

    const int wg   = blockIdx.x;
    const int tid  = threadIdx.x;
    const int wave = tid >> 6;
    const int lane = tid & 63;
    const int sub  = lane & 15;
    const int unit = wg * 8 + wave;
    const int row  = (lane >> 4) * HDIM + unit;  // gate = lane>>4

    for (int i = tid; i < TSTEPS; i += NTH) s_lds[i] = src[3 * i];
    for (int i = tid; i < HDIM;   i += NTH) wlin_lds[i] = W_lin[i];
    if (tid == 0) y_acc = 0.0f;

    const float s01  = src[1];
    const float s02  = src[2];
    const float blin = b_lin[0];

    const float w0    = W_ih[row * 3 + 0];
    const float w1    = W_ih[row * 3 + 1];
    const float w2    = W_ih[row * 3 + 2];
    const float w12   = w1 + w2;
    const float braw  = b_ih[row] + b_hh[row];
    const float bfold = braw + w12 * blin;

    FOR_K(DECLW)
    {
        const float* wrow = W_hh + (size_t)row * HDIM;
        FOR_K(INITW)
    }

    __syncthreads();

    float c_state = 0.0f;

    const int pbase = wave * 256 + lane;  // coalesced pull mapping
    const float wl0 = wlin_lds[pbase +   0];
    const float wl1 = wlin_lds[pbase +  64];
    const float wl2 = wlin_lds[pbase + 128];
    const float wl3 = wlin_lds[pbase + 192];

    for (int t = 0; t < TSTEPS; ++t) {
        const int wb = t & 1;       // buffer receiving h_t
        const int rb = wb ^ 1;      // buffer holding h_{t-1} (t>=1)

        float xterm;
        if (t == 0) {
            xterm = braw + w0 * s_lds[0] + w1 * s01 + w2 * s02;
        } else {
            xterm = bfold + w0 * s_lds[t];
        }

        float sum = 0.0f;
        if (t > 0) {
            float a0 = 0.0f, a1 = 0.0f, a2 = 0.0f, a3 = 0.0f;
            FOR_K(MACW)
            sum = (a0 + a1) + (a2 + a3);
            sum += __shfl_xor(sum, 1);
            sum += __shfl_xor(sum, 2);
            sum += __shfl_xor(sum, 4);
            sum += __shfl_xor(sum, 8);
        }

        // finalize y_{t-1}: owner of step t-1, after iter t-1's barrier
        if (t > 0 && wg == ((t - 1) & (NWG - 1)) && wave == 7 && lane == 0) {
            out[t - 1] = y_acc + blin;
            y_acc = 0.0f;  // next partials for this WG arrive at step t+255
        }

        const float gate = sum + xterm;
        const float gi = __shfl(gate, 0);
        const float gf = __shfl(gate, 16);
        const float gg = __shfl(gate, 32);
        const float go = __shfl(gate, 48);
        c_state = sigmoidf_(gf) * c_state + sigmoidf_(gi) * tanhf(gg);
        const float h_new = sigmoidf_(go) * tanhf(c_state);

        // publish h_t[unit]: single fused (tag | value) store
        u64* hb = h_buf + (size_t)wb * HDIM;
        if (lane == 0) {
            const u64 p = ((u64)(unsigned)(t + 1) << 32) |
                          (u64)__float_as_uint(h_new);
            __hip_atomic_store(&hb[unit], p,
                               __ATOMIC_RELAXED, __HIP_MEMORY_SCOPE_AGENT);
        }

        // pull 4 coalesced units of h_t (512 B contiguous per wave per instr)
        const unsigned want = (unsigned)(t + 1);
        u64 v0, v1, v2, v3;
        for (;;) {
            v0 = __hip_atomic_load(&hb[pbase +   0], __ATOMIC_RELAXED, __HIP_MEMORY_SCOPE_AGENT);
            v1 = __hip_atomic_load(&hb[pbase +  64], __ATOMIC_RELAXED, __HIP_MEMORY_SCOPE_AGENT);
            v2 = __hip_atomic_load(&hb[pbase + 128], __ATOMIC_RELAXED, __HIP_MEMORY_SCOPE_AGENT);
            v3 = __hip_atomic_load(&hb[pbase + 192], __ATOMIC_RELAXED, __HIP_MEMORY_SCOPE_AGENT);
            if ((unsigned)(v0 >> 32) == want && (unsigned)(v1 >> 32) == want &&
                (unsigned)(v2 >> 32) == want && (unsigned)(v3 >> 32) == want)
                break;
            __builtin_amdgcn_s_sleep(1);  // ~64 cycles
        }
        const float f0 = __uint_as_float((unsigned)v0);
        const float f1 = __uint_as_float((unsigned)v1);
        const float f2 = __uint_as_float((unsigned)v2);
        const float f3 = __uint_as_float((unsigned)v3);
        h_lds[wb][pbase +   0] = f0;
        h_lds[wb][pbase +  64] = f1;
        h_lds[wb][pbase + 128] = f2;
        h_lds[wb][pbase + 192] = f3;

        // y_t partials from registers (owner WG only; off critical path)
        if (wg == (t & (NWG - 1))) {
            float yp = f0 * wl0 + f1 * wl1 + f2 * wl2 + f3 * wl3;
            yp += __shfl_xor(yp, 1);
            yp += __shfl_xor(yp, 2);
            yp += __shfl_xor(yp, 4);
            yp += __shfl_xor(yp, 8);
            yp += __shfl_xor(yp, 16);
            yp += __shfl_xor(yp, 32);
            if (lane == 0) atomicAdd(&y_acc, yp);
        }

        __syncthreads();  // h_lds[wb] complete; also orders y_acc partials
    }

    // final y_{T-1}: owner wg = 255
    if (wg == ((TSTEPS - 1) & (NWG - 1)) && wave == 7 && lane == 0) {
        out[TSTEPS - 1] = y_acc + blin;
    }
}

extern "C" void kernel_launch(void* const* d_in, const int* in_sizes, int n_in,
                              void* d_out, int out_size, void* d_ws, size_t ws_size,
                              hipStream_t stream) {
    const float* src   = (const float*)d_in[0];
    const float* W_ih  = (const float*)d_in[1];
    const float* W_hh  = (const float*)d_in[2];
    const float* b_ih  = (const float*)d_in[3];
    const float* b_hh  = (const float*)d_in[4];
    const float* W_lin = (const float*)d_in[5];
    const float* b_lin = (const float*)d_in[6];
    float* out = (float*)d_out;

    // ws: [0, 32 KiB) = h_buf: 2 (parity) x 2048 x 8 B packed tag|value.
    // Cleared every launch so stale tags from a previous replay can't match.
    u64* h_buf = (u64*)d_ws;
    hipMemsetAsync(d_ws, 0, 2 * HDIM * sizeof(u64), stream);

    void* args[] = { &src, &W_ih, &W_hh, &b_ih, &b_hh, &W_lin, &b_lin,
                     &out, &h_buf };
    hipLaunchCooperativeKernel((const void*)weld_lstm_persistent,
                               dim3(NWG), dim3(NTH), args, 0, stream);
}

// Round 7
// 13412.285 us; speedup vs baseline: 2.9084x; 1.8564x over previous
//
#include <hip/hip_runtime.h>
#include <math.h>

// Persistent cooperative LSTM: 256 WGs x 512 threads, 1 WG/CU.
// WG w owns hidden units [8w, 8w+8). wave u = unit, 16-lane group g = gate.
// Folded weights W' = W_hh + (w1+w2) (x) W_lin (128/thread, compiler-managed).
//
// R7 change vs R4 (single-variable): PRODUCER side. R1-R6 had 8 different
// waves each storing 8B into the same 64B h_buf line -> partial-line
// write-through serialization at the coherence point (WRITE_SIZE showed 4x
// transaction amplification). Now: lane0 of each wave ds_writes h_new to
// hshare[wave]; a monotonic LDS fetch_add elects the LAST-arriving wave as
// storer (no barrier, no spin); its lanes 0-7 issue ONE wave-coalesced
// 64B full-line store of 8 fused ((t+1)<<32 | f32bits(h)) words.
//
// Consumer side unchanged from R4: all threads poll 4 coalesced units
// (wave*256+lane+64j) until tag==t+1 (s_sleep-throttled), write h_lds[t&1],
// ONE __syncthreads, next matvec reads h_lds. Exact-tag match + per-parity
// buffers kill ABA; per-launch memset kills graph-replay staleness.
//
// y_t: owner WG (t%256) dots pulled registers with W_lin into LDS y_acc;
// its wave7 writes out[t] during step t+1 (off the critical path).

#define HDIM 2048
#define TSTEPS 4096
#define NWG 256
#define NTH 512  // 8 waves

typedef unsigned long long u64;
typedef unsigned int u32;

__device__ __forceinline__ float sigmoidf_(float x) {
    return 1.0f / (1.0f + expf(-x));
}

__global__ __launch_bounds__(NTH, 2)
void weld_lstm_persistent(const float* __restrict__ src,
                          const float* __restrict__ W_ih,
                          const float* __restrict__ W_hh,
                          const float* __restrict__ b_ih,
                          const float* __restrict__ b_hh,
                          const float* __restrict__ W_lin,
                          const float* __restrict__ b_lin,
                          float* __restrict__ out,
                          u64* __restrict__ h_buf)
{
    __shared__ float h_lds[2][HDIM];
    __shared__ float s_lds[TSTEPS];
    __shared__ float wlin_lds[HDIM];
    __shared__ float hshare[8];   // this WG's 8 fresh h values
    __shared__ int   arrive_cnt;  // monotonic arrival counter (8 per step)
    __shared__ float y_acc;

    const int wg   = blockIdx.x;
    const int tid  = threadIdx.x;
    const int wave = tid >> 6;
    const int lane = tid & 63;
    const int g    = lane >> 4;        // gate 0..3 (i,f,g,o)
    const int sub  = lane & 15;
    const int unit = wg * 8 + wave;
    const int row  = g * HDIM + unit;

    for (int i = tid; i < TSTEPS; i += NTH) s_lds[i] = src[3 * i];
    for (int i = tid; i < HDIM;   i += NTH) wlin_lds[i] = W_lin[i];
    if (tid == 0) { y_acc = 0.0f; arrive_cnt = 0; }

    const float s01  = src[1];
    const float s02  = src[2];
    const float blin = b_lin[0];

    const float w0    = W_ih[row * 3 + 0];
    const float w1    = W_ih[row * 3 + 1];
    const float w2    = W_ih[row * 3 + 2];
    const float w12   = w1 + w2;
    const float braw  = b_ih[row] + b_hh[row];
    const float bfold = braw + w12 * blin;

    // Folded weights W'[row,c] = W_hh[row,c] + w12*W_lin[c]; this lane's
    // columns: c = k*64 + sub*4 + {0..3}, k = 0..31.
    float wreg[128];
    {
        const float* wrow = W_hh + (size_t)row * HDIM;
        #pragma unroll
        for (int k = 0; k < 32; ++k) {
            const int c = k * 64 + sub * 4;
            float4 wv = *reinterpret_cast<const float4*>(wrow + c);
            float4 lv = *reinterpret_cast<const float4*>(W_lin + c);
            wreg[k * 4 + 0] = wv.x + w12 * lv.x;
            wreg[k * 4 + 1] = wv.y + w12 * lv.y;
            wreg[k * 4 + 2] = wv.z + w12 * lv.z;
            wreg[k * 4 + 3] = wv.w + w12 * lv.w;
        }
    }

    __syncthreads();

    float c_state = 0.0f;

    const int pbase = wave * 256 + lane;  // coalesced pull mapping
    const float wl0 = wlin_lds[pbase +   0];
    const float wl1 = wlin_lds[pbase +  64];
    const float wl2 = wlin_lds[pbase + 128];
    const float wl3 = wlin_lds[pbase + 192];

    for (int t = 0; t < TSTEPS; ++t) {
        const int wb = t & 1;       // buffer receiving h_t
        const int rb = wb ^ 1;      // buffer holding h_{t-1} (t>=1)

        float xterm;
        if (t == 0) {
            xterm = braw + w0 * s_lds[0] + w1 * s01 + w2 * s02;
        } else {
            xterm = bfold + w0 * s_lds[t];
        }

        float sum = 0.0f;
        if (t > 0) {
            float a0 = 0.0f, a1 = 0.0f, a2 = 0.0f, a3 = 0.0f;
            #pragma unroll
            for (int k = 0; k < 32; ++k) {
                const int col = k * 64 + sub * 4;
                float4 h4 = *reinterpret_cast<const float4*>(&h_lds[rb][col]);
                a0 += wreg[k * 4 + 0] * h4.x;
                a1 += wreg[k * 4 + 1] * h4.y;
                a2 += wreg[k * 4 + 2] * h4.z;
                a3 += wreg[k * 4 + 3] * h4.w;
            }
            sum = (a0 + a1) + (a2 + a3);
            sum += __shfl_xor(sum, 1);
            sum += __shfl_xor(sum, 2);
            sum += __shfl_xor(sum, 4);
            sum += __shfl_xor(sum, 8);
        }

        // finalize y_{t-1}: owner of step t-1, after iter t-1's barrier
        if (t > 0 && wg == ((t - 1) & (NWG - 1)) && wave == 7 && lane == 0) {
            out[t - 1] = y_acc + blin;
            y_acc = 0.0f;  // next partials for this WG arrive at step t+255
        }

        const float gate = sum + xterm;
        const float gi = __shfl(gate, 0);
        const float gf = __shfl(gate, 16);
        const float gg = __shfl(gate, 32);
        const float go = __shfl(gate, 48);
        c_state = sigmoidf_(gf) * c_state + sigmoidf_(gi) * tanhf(gg);
        const float h_new = sigmoidf_(go) * tanhf(c_state);

        // ---- publish: gather 8 values in LDS, last-arriving wave does ONE
        //      coalesced full-line (64B) store of fused tag|value words ----
        u64* hb = h_buf + (size_t)wb * HDIM;
        int is_storer = 0;
        if (lane == 0) {
            hshare[wave] = h_new;
            // acq_rel: orders the hshare write before the counter bump, and
            // makes the winner's subsequent hshare reads see all 8 writes
            const int old = __hip_atomic_fetch_add(
                &arrive_cnt, 1, __ATOMIC_ACQ_REL,
                __HIP_MEMORY_SCOPE_WORKGROUP);
            is_storer = (old == 8 * t + 7);
        }
        is_storer = __shfl(is_storer, 0);
        if (is_storer && lane < 8) {
            const u64 p = ((u64)(unsigned)(t + 1) << 32) |
                          (u64)__float_as_uint(hshare[lane]);
            // lanes 0-7: 8B-consecutive -> one 64B full-line transaction
            __hip_atomic_store(&hb[wg * 8 + lane], p,
                               __ATOMIC_RELAXED, __HIP_MEMORY_SCOPE_AGENT);
        }

        // pull 4 coalesced units of h_t (512 B contiguous per wave per instr)
        const unsigned want = (unsigned)(t + 1);
        u64 v0, v1, v2, v3;
        for (;;) {
            v0 = __hip_atomic_load(&hb[pbase +   0], __ATOMIC_RELAXED, __HIP_MEMORY_SCOPE_AGENT);
            v1 = __hip_atomic_load(&hb[pbase +  64], __ATOMIC_RELAXED, __HIP_MEMORY_SCOPE_AGENT);
            v2 = __hip_atomic_load(&hb[pbase + 128], __ATOMIC_RELAXED, __HIP_MEMORY_SCOPE_AGENT);
            v3 = __hip_atomic_load(&hb[pbase + 192], __ATOMIC_RELAXED, __HIP_MEMORY_SCOPE_AGENT);
            if ((unsigned)(v0 >> 32) == want && (unsigned)(v1 >> 32) == want &&
                (unsigned)(v2 >> 32) == want && (unsigned)(v3 >> 32) == want)
                break;
            __builtin_amdgcn_s_sleep(1);  // ~64 cycles
        }
        const float f0 = __uint_as_float((unsigned)v0);
        const float f1 = __uint_as_float((unsigned)v1);
        const float f2 = __uint_as_float((unsigned)v2);
        const float f3 = __uint_as_float((unsigned)v3);
        h_lds[wb][pbase +   0] = f0;
        h_lds[wb][pbase +  64] = f1;
        h_lds[wb][pbase + 128] = f2;
        h_lds[wb][pbase + 192] = f3;

        // y_t partials from registers (owner WG only; off critical path)
        if (wg == (t & (NWG - 1))) {
            float yp = f0 * wl0 + f1 * wl1 + f2 * wl2 + f3 * wl3;
            yp += __shfl_xor(yp, 1);
            yp += __shfl_xor(yp, 2);
            yp += __shfl_xor(yp, 4);
            yp += __shfl_xor(yp, 8);
            yp += __shfl_xor(yp, 16);
            yp += __shfl_xor(yp, 32);
            if (lane == 0) atomicAdd(&y_acc, yp);
        }

        __syncthreads();  // h_lds[wb] complete; also orders y_acc partials
    }

    // final y_{T-1}: owner wg = 255
    if (wg == ((TSTEPS - 1) & (NWG - 1)) && wave == 7 && lane == 0) {
        out[TSTEPS - 1] = y_acc + blin;
    }
}

extern "C" void kernel_launch(void* const* d_in, const int* in_sizes, int n_in,
                              void* d_out, int out_size, void* d_ws, size_t ws_size,
                              hipStream_t stream) {
    const float* src   = (const float*)d_in[0];
    const float* W_ih  = (const float*)d_in[1];
    const float* W_hh  = (const float*)d_in[2];
    const float* b_ih  = (const float*)d_in[3];
    const float* b_hh  = (const float*)d_in[4];
    const float* W_lin = (const float*)d_in[5];
    const float* b_lin = (const float*)d_in[6];
    float* out = (float*)d_out;

    // ws: [0, 32 KiB) = h_buf: 2 (parity) x 2048 x 8 B packed tag|value.
    // Cleared every launch so stale tags from a previous replay can't match.
    u64* h_buf = (u64*)d_ws;
    hipMemsetAsync(d_ws, 0, 2 * HDIM * sizeof(u64), stream);

    void* args[] = { &src, &W_ih, &W_hh, &b_ih, &b_hh, &W_lin, &b_lin,
                     &out, &h_buf };
    hipLaunchCooperativeKernel((const void*)weld_lstm_persistent,
                               dim3(NWG), dim3(NTH), args, 0, stream);
}